// Round 15
// baseline (27.178 us; speedup 1.0000x reference)
//
#include <hip/hip_runtime.h>
#include <math.h>

// GaussianVisibility: R rays x B=24 bones x G=4 gaussians -> shadow map (R,)
// w2ls (R,24,4,4) fp32 = 100.7 MB stream. Validated model (R8-R14):
// dur = mem_floor(~16.3us, schedule-invariant; 11 overlap attempts null) +
// VALU_serial (~6.5us after R9+R12 diets; cuts convert ~1:1).
//
// R15 change vs R14 (22.28us): ILP probe. R14 ran the pair-loop at unroll 1
// (2 independent eval chains in flight); per-eval dep chain ~15 levels x 4-6
// cyc can leave issue bubbles even at 8 waves/SIMD (VALUBusy was 68%, not
// ~100%). unroll 2 -> 4 independent chains. ecarg negation folded. VGPR kept
// <=64 via launch_bounds(256,8). If neutral: declare practical ceiling.
//
// Layout (R4/R9): 8 lanes/ray, oct=(half,sub); lane owns matrix row sub,
// gaussian g=sub, bones of parity half, processed as 6 packed pairs
// (bA=2j+half, bB=2j+12+half). o/n rows shared via DPP quad_perm; halves
// merged with __shfl_xor(4). Cholesky params A/B-interleaved in LDS.

#define NB 24
#define NG 4
#define BASE_SCALE 0.001f

typedef float f2 __attribute__((ext_vector_type(2)));
#define PKF(a, b, c) __builtin_elementwise_fma((f2)(a), (f2)(b), (f2)(c))

template <int CTRL>
__device__ __forceinline__ float dpp_f(float x) {
    int r = __builtin_amdgcn_update_dpp(0, __float_as_int(x), CTRL, 0xF, 0xF, true);
    return __int_as_float(r);
}

__device__ __forceinline__ float frcp(float x) { return __builtin_amdgcn_rcpf(x); }
__device__ __forceinline__ float fexp2(float x) { return __builtin_amdgcn_exp2f(x); }

__global__ __launch_bounds__(256, 8) void gauss_vis_kernel(
    const float* __restrict__ w2ls,
    const float* __restrict__ rays_o,
    const float* __restrict__ rays_d,
    const float* __restrict__ Gs,
    float* __restrict__ out,
    int R)
{
    // Ppk[j][half][sub]: 5 float4 = 20 floats, A/B interleaved:
    // {u00A,u00B,u01A,u01B},{u02A,u02B,u11A,u11B},{u12A,u12B,u22A,u22B},
    // {mu0A,mu0B,mu1A,mu1B},{mu2A,mu2B,lcA,lcB}
    __shared__ float4 Ppk4[6 * 2 * 4 * 5];

    const int tid = threadIdx.x;
    const int gid = blockIdx.x * 256 + tid;
    const int ray0 = gid >> 3;
    const int ray = ray0 < R ? ray0 : (R - 1);
    const int oct = tid & 7;   // lane within the ray-octet
    const int sub = oct & 3;   // matrix row + gaussian index
    const int half = oct >> 2; // bone parity

    // ---- per-block param precompute (ray-independent): Cholesky + interleave ----
    if (tid < NB * NG) {
        const int b = tid >> 2, g = tid & 3;
        const float* gp = Gs + tid * 13;
        float mu0 = gp[0], mu1 = gp[1], mu2 = gp[2];
        float s0 = fabsf(gp[3]) + BASE_SCALE;
        float s1 = fabsf(gp[4]) + BASE_SCALE;
        float s2 = fabsf(gp[5]) + BASE_SCALE;
        float ax = gp[6], ay = gp[7], az = gp[8];
        float bx = gp[9], by = gp[10], bz = gp[11];
        float c = fabsf(gp[12]);
        float inv1 = 1.0f / sqrtf(ax * ax + ay * ay + az * az);
        float b1x = ax * inv1, b1y = ay * inv1, b1z = az * inv1;
        float dot = b1x * bx + b1y * by + b1z * bz;
        float t2x = bx - dot * b1x, t2y = by - dot * b1y, t2z = bz - dot * b1z;
        float inv2 = 1.0f / sqrtf(t2x * t2x + t2y * t2y + t2z * t2z);
        float b2x = t2x * inv2, b2y = t2y * inv2, b2z = t2z * inv2;
        float b3x = b1y * b2z - b1z * b2y;
        float b3y = b1z * b2x - b1x * b2z;
        float b3z = b1x * b2y - b1y * b2x;
        float w0 = 1.0f / (s0 * s0), w1 = 1.0f / (s1 * s1), w2 = 1.0f / (s2 * s2);
        float s00 = b1x * b1x * w0 + b1y * b1y * w1 + b1z * b1z * w2;
        float s01 = b1x * b2x * w0 + b1y * b2y * w1 + b1z * b2z * w2;
        float s02 = b1x * b3x * w0 + b1y * b3y * w1 + b1z * b3z * w2;
        float s11 = b2x * b2x * w0 + b2y * b2y * w1 + b2z * b2z * w2;
        float s12 = b2x * b3x * w0 + b2y * b3y * w1 + b2z * b3z * w2;
        float s22 = b3x * b3x * w0 + b3y * b3y * w1 + b3z * b3z * w2;
        // Cholesky S = U^T U (guarded)
        float u00 = sqrtf(fmaxf(s00, 1e-20f));
        float iu00 = 1.0f / u00;
        float u01 = s01 * iu00;
        float u02 = s02 * iu00;
        float u11 = sqrtf(fmaxf(s11 - u01 * u01, 1e-20f));
        float u12 = (s12 - u01 * u02) / u11;
        float u22 = sqrtf(fmaxf(s22 - u02 * u02 - u12 * u12, 1e-20f));
        float lc = log2f(c);
        // interleaved write: sel = (b>=12), j = (b-12*sel)>>1, hlf = b&1
        const int sel = b >= 12 ? 1 : 0;
        const int bb = b - 12 * sel;
        const int j = bb >> 1, hlf = b & 1;
        float* dst = (float*)&Ppk4[((j * 2 + hlf) * 4 + g) * 5];
        dst[0 * 2 + sel] = u00;  dst[1 * 2 + sel] = u01;
        dst[2 * 2 + sel] = u02;  dst[3 * 2 + sel] = u11;
        dst[4 * 2 + sel] = u12;  dst[5 * 2 + sel] = u22;
        dst[6 * 2 + sel] = mu0;  dst[7 * 2 + sel] = mu1;
        dst[8 * 2 + sel] = mu2;  dst[9 * 2 + sel] = lc;
    }
    __syncthreads();

    const float rox = rays_o[ray * 3 + 0];
    const float roy = rays_o[ray * 3 + 1];
    const float roz = rays_o[ray * 3 + 2];
    const float rdx = rays_d[ray * 3 + 0];
    const float rdy = rays_d[ray * 3 + 1];
    const float rdz = rays_d[ray * 3 + 2];

    const float4* __restrict__ Wp =
        (const float4*)w2ls + ((size_t)ray * 96 + half * 4 + sub);
    const float4* __restrict__ Pb = Ppk4 + (half * 4 + sub) * 5;

    const f2 C_ED  = {0.72134752f, 0.72134752f};   // log2e/2
    const f2 C_EWm = {-144.26950f, -144.26950f};   // -100*log2e
    const f2 C_EWb = {1.4426950f, 1.4426950f};     // log2e
    const f2 C_ECa = {-0.10180843f, -0.10180843f}; // -0.070566*log2e (folded neg)
    const f2 C_ECb = {-2.3048389f, -2.3048389f};   // -1.5976*log2e   (folded neg)
    const f2 C_ONE = {1.f, 1.f};
    const f2 C_TEN = {10.f, 10.f};

    f2 sum2 = {0.f, 0.f};
#pragma unroll 2
    for (int j = 0; j < 6; ++j) {
        const float4 MA = Wp[j * 8];        // bone 2j+half
        const float4 MB = Wp[j * 8 + 48];   // bone 2j+12+half
        float o_sA = fmaf(MA.x, rox, fmaf(MA.y, roy, fmaf(MA.z, roz, MA.w)));
        float o_sB = fmaf(MB.x, rox, fmaf(MB.y, roy, fmaf(MB.z, roz, MB.w)));
        float n_sA = fmaf(MA.x, rdx, fmaf(MA.y, rdy, MA.z * rdz));
        float n_sB = fmaf(MB.x, rdx, fmaf(MB.y, rdy, MB.z * rdz));
        f2 o0, o1, o2, n0, n1, n2;
        o0.x = dpp_f<0x00>(o_sA); o0.y = dpp_f<0x00>(o_sB);
        o1.x = dpp_f<0x55>(o_sA); o1.y = dpp_f<0x55>(o_sB);
        o2.x = dpp_f<0xAA>(o_sA); o2.y = dpp_f<0xAA>(o_sB);
        n0.x = dpp_f<0x00>(n_sA); n0.y = dpp_f<0x00>(n_sB);
        n1.x = dpp_f<0x55>(n_sA); n1.y = dpp_f<0x55>(n_sB);
        n2.x = dpp_f<0xAA>(n_sA); n2.y = dpp_f<0xAA>(n_sB);

        const float4* pp = Pb + j * 40;
        float4 q0 = pp[0], q1 = pp[1], q2 = pp[2], q3 = pp[3], q4 = pp[4];
        f2 u00 = ((const f2*)&q0)[0], u01 = ((const f2*)&q0)[1];
        f2 u02 = ((const f2*)&q1)[0], u11 = ((const f2*)&q1)[1];
        f2 u12 = ((const f2*)&q2)[0], u22 = ((const f2*)&q2)[1];
        f2 mu0 = ((const f2*)&q3)[0], mu1 = ((const f2*)&q3)[1];
        f2 mu2 = ((const f2*)&q4)[0], lc  = ((const f2*)&q4)[1];

        f2 d0 = mu0 - o0, d1 = mu1 - o1, d2 = mu2 - o2;   // mu - o
        f2 un0 = PKF(u02, n2, PKF(u01, n1, u00 * n0));    // U n
        f2 un1 = PKF(u12, n2, u11 * n1);
        f2 un2 = u22 * n2;
        f2 ud0 = PKF(u02, d2, PKF(u01, d1, u00 * d0));    // U d
        f2 ud1 = PKF(u12, d2, u11 * d1);
        f2 ud2 = u22 * d2;
        f2 nSn = PKF(un2, un2, PKF(un1, un1, un0 * un0)); // n^T S n
        f2 nSd = PKF(un2, ud2, PKF(un1, ud1, un0 * ud0)); // n^T S d
        f2 quad = PKF(ud2, ud2, PKF(ud1, ud1, ud0 * ud0));// d^T S d

        f2 r; r.x = __builtin_amdgcn_rsqf(nSn.x); r.y = __builtin_amdgcn_rsqf(nSn.y);
        f2 t = nSd * r;
        f2 resid = PKF(t, t, -quad);                      // 2*exponent (<=0)
        f2 mean = t * r;
        f2 edarg = PKF(C_ED, resid, lc);                  // log2(c*exp(resid/2))
        f2 ewarg = PKF(mean, C_EWm, C_EWb);               // log2(exp(1-100*mean))
        f2 z = r * PKF(nSn, C_TEN, -nSd);                 // (10-mean)*sqrt(nSn)
        f2 zz = z * z;
        f2 ecarg = z * PKF(C_ECa, zz, C_ECb);             // -z*(2.3+0.1*z^2)
        f2 ed, ew, ec;
        ed.x = fexp2(edarg.x); ed.y = fexp2(edarg.y);
        ew.x = fexp2(ewarg.x); ew.y = fexp2(ewarg.y);
        ec.x = fexp2(ecarg.x); ec.y = fexp2(ecarg.y);
        f2 den = (C_ONE + ew) * (C_ONE + ec);
        f2 rd; rd.x = frcp(den.x); rd.y = frcp(den.y);
        sum2 = PKF(ed, rd, sum2);
    }
    float sum = sum2.x + sum2.y;

    // reduce: quad butterfly (DPP), then merge the two quads of the octet
    sum += dpp_f<0xB1>(sum);       // quad_perm(1,0,3,2)
    sum += dpp_f<0x4E>(sum);       // quad_perm(2,3,0,1)
    sum += __shfl_xor(sum, 4, 64); // half <-> half
    if (oct == 0 && ray0 < R) out[ray0] = __expf(-sum);
}

extern "C" void kernel_launch(void* const* d_in, const int* in_sizes, int n_in,
                              void* d_out, int out_size, void* d_ws, size_t ws_size,
                              hipStream_t stream) {
    const float* w2ls   = (const float*)d_in[0];
    const float* rays_o = (const float*)d_in[1];
    const float* rays_d = (const float*)d_in[2];
    const float* Gs     = (const float*)d_in[3];
    float* out = (float*)d_out;

    const int R = in_sizes[1] / 3;
    const int threads = 256;
    const long long total = (long long)R * 8;
    const int blocks = (int)((total + threads - 1) / threads);
    gauss_vis_kernel<<<blocks, threads, 0, stream>>>(w2ls, rays_o, rays_d, Gs, out, R);
}

// Round 16
// 22.215 us; speedup vs baseline: 1.2234x; 1.2234x over previous
//
#include <hip/hip_runtime.h>
#include <math.h>

// GaussianVisibility: R rays x B=24 bones x G=4 gaussians -> shadow map (R,)
// w2ls (R,24,4,4) fp32 = 100.7 MB stream. Validated model (R8-R15):
// dur = mem_floor(~16.3us, schedule-invariant; 11 overlap attempts null) +
// VALU_serial (~6.2us after R9+R12 diets; cuts convert ~1:1).
// R15 (unroll 2) regressed to 27.2 (VGPR spill under the 64-reg cap) ->
// R16 = exact revert to R14 (22.28us best), the model-floor kernel.
//
// Kernel structure:
//  - 8 lanes/ray, oct=(half,sub); lane owns matrix row sub, gaussian g=sub,
//    bones of parity half, processed as 6 packed pairs (bA=2j+half,
//    bB=2j+12+half); f2 (ext_vector) math between broadcasts and trans.
//  - o/n rows shared across each quad via DPP quad_perm (VALU-only).
//  - Per-(b,g) Cholesky factor U (S = U^T U), computed once per block,
//    stored A/B-interleaved in LDS so ds_read_b128 yields f2 operands.
//  - exp2-domain transcendentals (constants pre-multiplied by log2 e);
//    c folded as lc=log2(c) into the density exponent.
//  - cubic-logistic normal CDF (|err|<1.5e-4), sigmoid via exp2+rcp,
//    merged denominator (1 rcp).
//  - Octet reduce: 2 DPP butterflies + __shfl_xor(4); lane 0 stores.

#define NB 24
#define NG 4
#define BASE_SCALE 0.001f

typedef float f2 __attribute__((ext_vector_type(2)));
#define PKF(a, b, c) __builtin_elementwise_fma((f2)(a), (f2)(b), (f2)(c))

template <int CTRL>
__device__ __forceinline__ float dpp_f(float x) {
    int r = __builtin_amdgcn_update_dpp(0, __float_as_int(x), CTRL, 0xF, 0xF, true);
    return __int_as_float(r);
}

__device__ __forceinline__ float frcp(float x) { return __builtin_amdgcn_rcpf(x); }
__device__ __forceinline__ float fexp2(float x) { return __builtin_amdgcn_exp2f(x); }

__global__ __launch_bounds__(256, 8) void gauss_vis_kernel(
    const float* __restrict__ w2ls,
    const float* __restrict__ rays_o,
    const float* __restrict__ rays_d,
    const float* __restrict__ Gs,
    float* __restrict__ out,
    int R)
{
    // Ppk[j][half][sub]: 5 float4 = 20 floats, A/B interleaved:
    // {u00A,u00B,u01A,u01B},{u02A,u02B,u11A,u11B},{u12A,u12B,u22A,u22B},
    // {mu0A,mu0B,mu1A,mu1B},{mu2A,mu2B,lcA,lcB}
    __shared__ float4 Ppk4[6 * 2 * 4 * 5];

    const int tid = threadIdx.x;
    const int gid = blockIdx.x * 256 + tid;
    const int ray0 = gid >> 3;
    const int ray = ray0 < R ? ray0 : (R - 1);
    const int oct = tid & 7;   // lane within the ray-octet
    const int sub = oct & 3;   // matrix row + gaussian index
    const int half = oct >> 2; // bone parity

    // ---- per-block param precompute (ray-independent): Cholesky + interleave ----
    if (tid < NB * NG) {
        const int b = tid >> 2, g = tid & 3;
        const float* gp = Gs + tid * 13;
        float mu0 = gp[0], mu1 = gp[1], mu2 = gp[2];
        float s0 = fabsf(gp[3]) + BASE_SCALE;
        float s1 = fabsf(gp[4]) + BASE_SCALE;
        float s2 = fabsf(gp[5]) + BASE_SCALE;
        float ax = gp[6], ay = gp[7], az = gp[8];
        float bx = gp[9], by = gp[10], bz = gp[11];
        float c = fabsf(gp[12]);
        float inv1 = 1.0f / sqrtf(ax * ax + ay * ay + az * az);
        float b1x = ax * inv1, b1y = ay * inv1, b1z = az * inv1;
        float dot = b1x * bx + b1y * by + b1z * bz;
        float t2x = bx - dot * b1x, t2y = by - dot * b1y, t2z = bz - dot * b1z;
        float inv2 = 1.0f / sqrtf(t2x * t2x + t2y * t2y + t2z * t2z);
        float b2x = t2x * inv2, b2y = t2y * inv2, b2z = t2z * inv2;
        float b3x = b1y * b2z - b1z * b2y;
        float b3y = b1z * b2x - b1x * b2z;
        float b3z = b1x * b2y - b1y * b2x;
        float w0 = 1.0f / (s0 * s0), w1 = 1.0f / (s1 * s1), w2 = 1.0f / (s2 * s2);
        float s00 = b1x * b1x * w0 + b1y * b1y * w1 + b1z * b1z * w2;
        float s01 = b1x * b2x * w0 + b1y * b2y * w1 + b1z * b2z * w2;
        float s02 = b1x * b3x * w0 + b1y * b3y * w1 + b1z * b3z * w2;
        float s11 = b2x * b2x * w0 + b2y * b2y * w1 + b2z * b2z * w2;
        float s12 = b2x * b3x * w0 + b2y * b3y * w1 + b2z * b3z * w2;
        float s22 = b3x * b3x * w0 + b3y * b3y * w1 + b3z * b3z * w2;
        // Cholesky S = U^T U (guarded)
        float u00 = sqrtf(fmaxf(s00, 1e-20f));
        float iu00 = 1.0f / u00;
        float u01 = s01 * iu00;
        float u02 = s02 * iu00;
        float u11 = sqrtf(fmaxf(s11 - u01 * u01, 1e-20f));
        float u12 = (s12 - u01 * u02) / u11;
        float u22 = sqrtf(fmaxf(s22 - u02 * u02 - u12 * u12, 1e-20f));
        float lc = log2f(c);
        // interleaved write: sel = (b>=12), j = (b-12*sel)>>1, hlf = b&1
        const int sel = b >= 12 ? 1 : 0;
        const int bb = b - 12 * sel;
        const int j = bb >> 1, hlf = b & 1;
        float* dst = (float*)&Ppk4[((j * 2 + hlf) * 4 + g) * 5];
        dst[0 * 2 + sel] = u00;  dst[1 * 2 + sel] = u01;
        dst[2 * 2 + sel] = u02;  dst[3 * 2 + sel] = u11;
        dst[4 * 2 + sel] = u12;  dst[5 * 2 + sel] = u22;
        dst[6 * 2 + sel] = mu0;  dst[7 * 2 + sel] = mu1;
        dst[8 * 2 + sel] = mu2;  dst[9 * 2 + sel] = lc;
    }
    __syncthreads();

    const float rox = rays_o[ray * 3 + 0];
    const float roy = rays_o[ray * 3 + 1];
    const float roz = rays_o[ray * 3 + 2];
    const float rdx = rays_d[ray * 3 + 0];
    const float rdy = rays_d[ray * 3 + 1];
    const float rdz = rays_d[ray * 3 + 2];

    const float4* __restrict__ Wp =
        (const float4*)w2ls + ((size_t)ray * 96 + half * 4 + sub);
    const float4* __restrict__ Pb = Ppk4 + (half * 4 + sub) * 5;

    const f2 C_ED  = {0.72134752f, 0.72134752f};   // log2e/2
    const f2 C_EWm = {-144.26950f, -144.26950f};   // -100*log2e
    const f2 C_EWb = {1.4426950f, 1.4426950f};     // log2e
    const f2 C_ECa = {0.10180843f, 0.10180843f};   // 0.070566*log2e
    const f2 C_ECb = {2.3048389f, 2.3048389f};     // 1.5976*log2e
    const f2 C_ONE = {1.f, 1.f};
    const f2 C_TEN = {10.f, 10.f};

    f2 sum2 = {0.f, 0.f};
#pragma unroll 1
    for (int j = 0; j < 6; ++j) {
        const float4 MA = Wp[j * 8];        // bone 2j+half
        const float4 MB = Wp[j * 8 + 48];   // bone 2j+12+half
        float o_sA = fmaf(MA.x, rox, fmaf(MA.y, roy, fmaf(MA.z, roz, MA.w)));
        float o_sB = fmaf(MB.x, rox, fmaf(MB.y, roy, fmaf(MB.z, roz, MB.w)));
        float n_sA = fmaf(MA.x, rdx, fmaf(MA.y, rdy, MA.z * rdz));
        float n_sB = fmaf(MB.x, rdx, fmaf(MB.y, rdy, MB.z * rdz));
        f2 o0, o1, o2, n0, n1, n2;
        o0.x = dpp_f<0x00>(o_sA); o0.y = dpp_f<0x00>(o_sB);
        o1.x = dpp_f<0x55>(o_sA); o1.y = dpp_f<0x55>(o_sB);
        o2.x = dpp_f<0xAA>(o_sA); o2.y = dpp_f<0xAA>(o_sB);
        n0.x = dpp_f<0x00>(n_sA); n0.y = dpp_f<0x00>(n_sB);
        n1.x = dpp_f<0x55>(n_sA); n1.y = dpp_f<0x55>(n_sB);
        n2.x = dpp_f<0xAA>(n_sA); n2.y = dpp_f<0xAA>(n_sB);

        const float4* pp = Pb + j * 40;
        float4 q0 = pp[0], q1 = pp[1], q2 = pp[2], q3 = pp[3], q4 = pp[4];
        f2 u00 = ((const f2*)&q0)[0], u01 = ((const f2*)&q0)[1];
        f2 u02 = ((const f2*)&q1)[0], u11 = ((const f2*)&q1)[1];
        f2 u12 = ((const f2*)&q2)[0], u22 = ((const f2*)&q2)[1];
        f2 mu0 = ((const f2*)&q3)[0], mu1 = ((const f2*)&q3)[1];
        f2 mu2 = ((const f2*)&q4)[0], lc  = ((const f2*)&q4)[1];

        f2 d0 = mu0 - o0, d1 = mu1 - o1, d2 = mu2 - o2;   // mu - o
        f2 un0 = PKF(u02, n2, PKF(u01, n1, u00 * n0));    // U n
        f2 un1 = PKF(u12, n2, u11 * n1);
        f2 un2 = u22 * n2;
        f2 ud0 = PKF(u02, d2, PKF(u01, d1, u00 * d0));    // U d
        f2 ud1 = PKF(u12, d2, u11 * d1);
        f2 ud2 = u22 * d2;
        f2 nSn = PKF(un2, un2, PKF(un1, un1, un0 * un0)); // n^T S n
        f2 nSd = PKF(un2, ud2, PKF(un1, ud1, un0 * ud0)); // n^T S d
        f2 quad = PKF(ud2, ud2, PKF(ud1, ud1, ud0 * ud0));// d^T S d

        f2 r; r.x = __builtin_amdgcn_rsqf(nSn.x); r.y = __builtin_amdgcn_rsqf(nSn.y);
        f2 t = nSd * r;
        f2 resid = PKF(t, t, -quad);                      // 2*exponent (<=0)
        f2 mean = t * r;
        f2 edarg = PKF(C_ED, resid, lc);                  // log2(c*exp(resid/2))
        f2 ewarg = PKF(mean, C_EWm, C_EWb);               // log2(exp(1-100*mean))
        f2 zi = PKF(nSn, C_TEN, -nSd);
        f2 z = zi * r;                                    // (10-mean)*sqrt(nSn)
        f2 zz = z * z;
        f2 ecarg = -z * PKF(C_ECa, zz, C_ECb);            // cubic-logistic Phi
        f2 ed, ew, ec;
        ed.x = fexp2(edarg.x); ed.y = fexp2(edarg.y);
        ew.x = fexp2(ewarg.x); ew.y = fexp2(ewarg.y);
        ec.x = fexp2(ecarg.x); ec.y = fexp2(ecarg.y);
        f2 den = (C_ONE + ew) * (C_ONE + ec);
        f2 rd; rd.x = frcp(den.x); rd.y = frcp(den.y);
        sum2 = PKF(ed, rd, sum2);
    }
    float sum = sum2.x + sum2.y;

    // reduce: quad butterfly (DPP), then merge the two quads of the octet
    sum += dpp_f<0xB1>(sum);       // quad_perm(1,0,3,2)
    sum += dpp_f<0x4E>(sum);       // quad_perm(2,3,0,1)
    sum += __shfl_xor(sum, 4, 64); // half <-> half
    if (oct == 0 && ray0 < R) out[ray0] = __expf(-sum);
}

extern "C" void kernel_launch(void* const* d_in, const int* in_sizes, int n_in,
                              void* d_out, int out_size, void* d_ws, size_t ws_size,
                              hipStream_t stream) {
    const float* w2ls   = (const float*)d_in[0];
    const float* rays_o = (const float*)d_in[1];
    const float* rays_d = (const float*)d_in[2];
    const float* Gs     = (const float*)d_in[3];
    float* out = (float*)d_out;

    const int R = in_sizes[1] / 3;
    const int threads = 256;
    const long long total = (long long)R * 8;
    const int blocks = (int)((total + threads - 1) / threads);
    gauss_vis_kernel<<<blocks, threads, 0, stream>>>(w2ls, rays_o, rays_d, Gs, out, R);
}